// Round 8
// baseline (135.456 us; speedup 1.0000x reference)
//
#include <hip/hip_runtime.h>
#include <math.h>

// HiPPO-LegS kernel: K[d, l] = C[d]^T A_bar^l B_bar[d], D=1024, N=64, L=4096.
// l = 64q + r decomposition; G_r = A_bar^r, H_q = (A_bar^64)^q via squarings
// S_j = A_bar^(2^j), j=0..11.  All products: mfma_f32_16x16x32_bf16 with
// split-bf16 hi/lo 3-term (exact vs R7).
// Round 8: staging-LDS removed from expand/contract/powers-B — MFMA fragments
// are loaded DIRECTLY from global (pre-split bf16 planes / fp32 split in
// regs). k_expand batches 4 d-chunks per block with register-resident B-frags.
// k_powers keeps LDS only for chain intermediates (A-layout only).
// k_setup: Bt-half of dstore vectorized to ds_write_b64.

#define BPAD 72  // bf16 LDS row stride in ushorts (144 B)
#define ARR (64 * BPAD)

// ws layout (float offsets).
#define WS_BBAR   16                      // 1024x64 fp32
#define WS_SPL    65552                   // 12 x 8192: [hi|lo|thi|tlo] x 2048 floats
#define WS_MV     (WS_SPL + 12*8192)      // MvHi 2048, MvLo 2048
#define WS_GT     (WS_MV + 4096)          // 64 x 4096 (hi 2048 | lo 2048)
#define WS_H      (WS_GT + 64*4096)       // 64 x 4096 (hi | lo)
#define WS_W      (WS_H + 64*4096)        // [d][r][n] fp32
#define WS_X      (WS_W + 1024*4096)      // [d][q][n] fp32

using bf16x8 = __attribute__((ext_vector_type(8))) short;
using f32x4v = __attribute__((ext_vector_type(4))) float;
typedef unsigned short ushort_t;

__device__ __forceinline__ ushort_t f2bf(float x) {
  unsigned u = __builtin_bit_cast(unsigned, x);
  return (ushort_t)((u + 0x7FFFu + ((u >> 16) & 1u)) >> 16);
}
__device__ __forceinline__ float bfhi(float x) {
  unsigned u = __builtin_bit_cast(unsigned, x);
  unsigned r = (u + 0x7FFFu + ((u >> 16) & 1u)) & 0xFFFF0000u;
  return __builtin_bit_cast(float, r);
}
__device__ __forceinline__ ushort_t* usp(float* ws, int foff) {
  return (ushort_t*)(ws + foff);
}
__device__ __forceinline__ const ushort_t* uspc(const float* ws, int foff) {
  return (const ushort_t*)(ws + foff);
}

// 8 consecutive fp32 (32B-aligned) -> split hi/lo bf16 frags, in registers.
__device__ __forceinline__ void ldsplit8(const float* __restrict__ p,
                                         bf16x8& h, bf16x8& l) {
  const float4 a = *(const float4*)p;
  const float4 b = *(const float4*)(p + 4);
  const float v[8] = {a.x, a.y, a.z, a.w, b.x, b.y, b.z, b.w};
#pragma unroll
  for (int i = 0; i < 8; ++i) {
    h[i] = (short)f2bf(v[i]);
    l[i] = (short)f2bf(v[i] - bfhi(v[i]));
  }
}

// ---- LDS-operand MFMA (k_setup only): D[m][n] = sum_k A[m][k]*Bt[n][k] ----
__device__ __forceinline__ void mm_frag(const ushort_t* __restrict__ Ah,
                                        const ushort_t* __restrict__ Al,
                                        const ushort_t* __restrict__ Bh,
                                        const ushort_t* __restrict__ Bl,
                                        int w, int lane, f32x4v acc[4]) {
  const int lm = lane & 15, quad = lane >> 4;
  const int ar = (16 * w + lm) * BPAD, ko = quad * 8;
#pragma unroll
  for (int nt = 0; nt < 4; ++nt) { acc[nt][0] = acc[nt][1] = acc[nt][2] = acc[nt][3] = 0.f; }
#pragma unroll
  for (int kc = 0; kc < 64; kc += 32) {
    const bf16x8 ahi = *(const bf16x8*)&Ah[ar + kc + ko];
    const bf16x8 alo = *(const bf16x8*)&Al[ar + kc + ko];
#pragma unroll
    for (int nt = 0; nt < 4; ++nt) {
      const int br = (16 * nt + lm) * BPAD + kc + ko;
      const bf16x8 bhi = *(const bf16x8*)&Bh[br];
      const bf16x8 blo = *(const bf16x8*)&Bl[br];
      acc[nt] = __builtin_amdgcn_mfma_f32_16x16x32_bf16(ahi, bhi, acc[nt], 0, 0, 0);
      acc[nt] = __builtin_amdgcn_mfma_f32_16x16x32_bf16(ahi, blo, acc[nt], 0, 0, 0);
      acc[nt] = __builtin_amdgcn_mfma_f32_16x16x32_bf16(alo, bhi, acc[nt], 0, 0, 0);
    }
  }
}

// D regs -> split bf16 LDS, A-layout (scalar) + Bt-layout (b64-packed).
__device__ __forceinline__ void dstore_lds(const f32x4v acc[4],
                                           ushort_t* __restrict__ Ah, ushort_t* __restrict__ Al,
                                           ushort_t* __restrict__ Bth, ushort_t* __restrict__ Btl,
                                           int w, int lane) {
  const int lm = lane & 15, quad = lane >> 4;
  const int m0 = 16 * w + 4 * quad;
#pragma unroll
  for (int nt = 0; nt < 4; ++nt) {
    const int n = 16 * nt + lm;
    ushort_t h[4], l[4];
#pragma unroll
    for (int reg = 0; reg < 4; ++reg) {
      const float x = acc[nt][reg];
      h[reg] = f2bf(x); l[reg] = f2bf(x - bfhi(x));
      Ah[(m0 + reg) * BPAD + n] = h[reg];
      Al[(m0 + reg) * BPAD + n] = l[reg];
    }
    uint2 hp, lp;
    hp.x = (unsigned)h[0] | ((unsigned)h[1] << 16);
    hp.y = (unsigned)h[2] | ((unsigned)h[3] << 16);
    lp.x = (unsigned)l[0] | ((unsigned)l[1] << 16);
    lp.y = (unsigned)l[2] | ((unsigned)l[3] << 16);
    *(uint2*)&Bth[n * BPAD + m0] = hp;
    *(uint2*)&Btl[n * BPAD + m0] = lp;
  }
}

// packed 64x64 ushort ws region <- padded LDS, 256 threads
__device__ __forceinline__ void cp_l2w(const ushort_t* __restrict__ l,
                                       ushort_t* __restrict__ g, int tid) {
  for (int e = tid; e < 512; e += 256) {
    const int row = e >> 3, c8 = (e & 7) * 8;
    *(uint4*)&g[row * 64 + c8] = *(const uint4*)&l[row * BPAD + c8];
  }
}

// ---------------------------------------------------------------------------
// K1: one block, 256 threads. fp32 recursive-doubling inverse of lower-tri M
// (diag >= 1.05); A_bar = 2*Minv - I; 11 MFMA split-bf16 squarings, state as
// hi/lo bf16 in A + Bt LDS layouts. Exports S_j / S_j^T / Minv (split).
// ---------------------------------------------------------------------------
__global__ __launch_bounds__(256) void k_setup(const float* __restrict__ A,
                                               const float* __restrict__ logdt,
                                               float* __restrict__ ws) {
  __shared__ __align__(16) char SM[74240];
  float* Msh = (float*)SM;                    // 64*65 fp32, dead after phase 2
  float* Tm  = (float*)(SM + 16640);          // 64*65 fp32 (becomes Minv)
  float* tmpb = (float*)(SM + 33280);         // 1024 fp32
  ushort_t* ping = (ushort_t*)(SM + 37376);   // 4 arrays of ARR
  ushort_t* pong = (ushort_t*)SM;             // overlays Msh/Tm/tmpb (dead then)
  const int tid = threadIdx.x;
  const int w = tid >> 6, lane = tid & 63;

  const float hdt = 0.5f * expf(logdt[0]);
  for (int idx = tid; idx < 4096; idx += 256) {
    const int i = idx >> 6, j = idx & 63;
    Msh[i * 65 + j] = ((i == j) ? 1.f : 0.f) - hdt * A[idx];
    Tm[i * 65 + j] = 0.f;
  }
  __syncthreads();
  if (tid < 64) Tm[tid * 65 + tid] = 1.0f / Msh[tid * 65 + tid];
  __syncthreads();
  for (int lb = 0; lb < 6; ++lb) {
    const int b = 1 << lb;
    const int E = 32 * b;
    for (int e = tid; e < E; e += 256) {
      const int rem = e & (b * b - 1);
      const int p = e >> (2 * lb);
      const int i = rem >> lb, j = rem & (b - 1);
      const int c0 = p << (lb + 1), r0 = c0 + b;
      float s = 0.f;
      for (int k = 0; k < b; ++k)
        s += Msh[(r0 + i) * 65 + c0 + k] * Tm[(c0 + k) * 65 + c0 + j];
      tmpb[e] = s;
    }
    __syncthreads();
    for (int e = tid; e < E; e += 256) {
      const int rem = e & (b * b - 1);
      const int p = e >> (2 * lb);
      const int i = rem >> lb, j = rem & (b - 1);
      const int c0 = p << (lb + 1), r0 = c0 + b;
      float s = 0.f;
      const float* tp = &tmpb[e - rem];
      for (int k = 0; k < b; ++k)
        s += Tm[(r0 + i) * 65 + r0 + k] * tp[k * b + j];
      Tm[(r0 + i) * 65 + c0 + j] = -s;
    }
    __syncthreads();
  }

  {
    ushort_t* MvH = usp(ws, WS_MV);
    ushort_t* MvL = usp(ws, WS_MV + 2048);
    for (int idx = tid; idx < 4096; idx += 256) {
      const int i = idx >> 6, j = idx & 63;
      const float mv = Tm[i * 65 + j];
      MvH[idx] = f2bf(mv); MvL[idx] = f2bf(mv - bfhi(mv));
      const float v = 2.f * mv - ((i == j) ? 1.f : 0.f);
      const ushort_t h = f2bf(v), l = f2bf(v - bfhi(v));
      ping[0 * ARR + i * BPAD + j] = h; ping[1 * ARR + i * BPAD + j] = l;
      ping[2 * ARR + j * BPAD + i] = h; ping[3 * ARR + j * BPAD + i] = l;
    }
  }
  __syncthreads();
  cp_l2w(ping + 0 * ARR, usp(ws, WS_SPL + 0), tid);
  cp_l2w(ping + 1 * ARR, usp(ws, WS_SPL + 2048), tid);
  cp_l2w(ping + 2 * ARR, usp(ws, WS_SPL + 4096), tid);
  cp_l2w(ping + 3 * ARR, usp(ws, WS_SPL + 6144), tid);

  ushort_t* cur = ping;
  ushort_t* nxt = pong;
  for (int sj = 1; sj < 12; ++sj) {
    f32x4v acc[4];
    mm_frag(cur, cur + ARR, cur + 2 * ARR, cur + 3 * ARR, w, lane, acc);
    dstore_lds(acc, nxt, nxt + ARR, nxt + 2 * ARR, nxt + 3 * ARR, w, lane);
    __syncthreads();
    const int base = WS_SPL + sj * 8192;
    cp_l2w(nxt + 0 * ARR, usp(ws, base + 0), tid);
    cp_l2w(nxt + 1 * ARR, usp(ws, base + 2048), tid);
    cp_l2w(nxt + 2 * ARR, usp(ws, base + 4096), tid);
    cp_l2w(nxt + 3 * ARR, usp(ws, base + 6144), tid);
    ushort_t* t = cur; cur = nxt; nxt = t;
  }
}

// ---------------------------------------------------------------------------
// K2: 144 blocks x 256. Direct-global B operands; LDS only for chain
// intermediates (A-layout hi/lo, ping-pong).
//  p in [0,64):   Gt_r  p in [64,128): H_q   p in [128,144): B_bar chunk.
// ---------------------------------------------------------------------------
__global__ __launch_bounds__(256) void k_powers(const float* __restrict__ Bg,
                                                const float* __restrict__ logdt,
                                                float* __restrict__ ws) {
  __shared__ __align__(16) ushort_t Pl[4 * ARR];  // 2 bufs x (hi|lo), 36.9 KB
  const int p = blockIdx.x, tid = threadIdx.x;
  const int w = tid >> 6, lane = tid & 63;
  const int lm = lane & 15, quad = lane >> 4;

  if (p < 128) {
    const int chain = p >> 6, r = p & 63;
    ushort_t* dstH = usp(ws, (chain ? WS_H : WS_GT) + r * 4096);
    ushort_t* dstL = usp(ws, (chain ? WS_H : WS_GT) + r * 4096 + 2048);
    if (r == 0) {
      for (int idx = tid; idx < 4096; idx += 256) {
        const int i = idx >> 6, j = idx & 63;
        dstH[idx] = (i == j) ? (ushort_t)0x3F80 : (ushort_t)0;
        dstL[idx] = 0;
      }
      return;
    }
    const int j0 = __ffs(r) - 1;
    if (r == (1 << j0)) {
      const int sb = WS_SPL + (chain * 6 + j0) * 8192;
      const int src = chain ? sb : (sb + 4096);  // chain0: St, chain1: S
      const uint4* sh = (const uint4*)uspc(ws, src);
      const uint4* sl = (const uint4*)uspc(ws, src + 2048);
      uint4* dh = (uint4*)dstH;
      uint4* dl = (uint4*)dstL;
      for (int e = tid; e < 512; e += 256) { dh[e] = sh[e]; dl[e] = sl[e]; }
      return;
    }
    // multi-bit chain: P <- S_{j0}; P <- P * S_j for higher set bits.
    const int sb0 = WS_SPL + (chain * 6 + j0) * 8192;
    const ushort_t* A0h = uspc(ws, sb0);
    const ushort_t* A0l = uspc(ws, sb0 + 2048);
    int cur = -1;
    for (int j = j0 + 1; j < 6; ++j) {
      if (!((r >> j) & 1)) continue;
      const int sb = WS_SPL + (chain * 6 + j) * 8192;
      const ushort_t* BtH = uspc(ws, sb + 4096);
      const ushort_t* BtL = uspc(ws, sb + 6144);
      f32x4v acc[4];
#pragma unroll
      for (int nt = 0; nt < 4; ++nt) { acc[nt][0] = acc[nt][1] = acc[nt][2] = acc[nt][3] = 0.f; }
#pragma unroll
      for (int c = 0; c < 2; ++c) {
        bf16x8 ahi, alo;
        if (cur < 0) {
          const int off = (16 * w + lm) * 64 + c * 32 + quad * 8;
          ahi = *(const bf16x8*)&A0h[off];
          alo = *(const bf16x8*)&A0l[off];
        } else {
          const ushort_t* Ph = Pl + cur * 2 * ARR;
          const int off = (16 * w + lm) * BPAD + c * 32 + quad * 8;
          ahi = *(const bf16x8*)&Ph[off];
          alo = *(const bf16x8*)&Ph[ARR + off];
        }
#pragma unroll
        for (int nt = 0; nt < 4; ++nt) {
          const int off = (16 * nt + lm) * 64 + c * 32 + quad * 8;
          const bf16x8 bh = *(const bf16x8*)&BtH[off];
          const bf16x8 bl = *(const bf16x8*)&BtL[off];
          acc[nt] = __builtin_amdgcn_mfma_f32_16x16x32_bf16(ahi, bh, acc[nt], 0, 0, 0);
          acc[nt] = __builtin_amdgcn_mfma_f32_16x16x32_bf16(ahi, bl, acc[nt], 0, 0, 0);
          acc[nt] = __builtin_amdgcn_mfma_f32_16x16x32_bf16(alo, bh, acc[nt], 0, 0, 0);
        }
      }
      if (r >> (j + 1)) {  // more products follow: park P in LDS (A-layout)
        const int nb = (cur < 0) ? 0 : (cur ^ 1);
        ushort_t* Ph = Pl + nb * 2 * ARR;
#pragma unroll
        for (int nt = 0; nt < 4; ++nt) {
          const int n = 16 * nt + lm;
#pragma unroll
          for (int reg = 0; reg < 4; ++reg) {
            const int m = 16 * w + 4 * quad + reg;
            const float x = acc[nt][reg];
            Ph[m * BPAD + n] = f2bf(x);
            Ph[ARR + m * BPAD + n] = f2bf(x - bfhi(x));
          }
        }
        __syncthreads();
        cur = nb;
      } else {  // final: export
        if (chain == 0) {  // Gt = P^T: [n][m], b64-packed over reg
          const int m0 = 16 * w + 4 * quad;
#pragma unroll
          for (int nt = 0; nt < 4; ++nt) {
            const int n = 16 * nt + lm;
            ushort_t h[4], l[4];
#pragma unroll
            for (int reg = 0; reg < 4; ++reg) {
              const float x = acc[nt][reg];
              h[reg] = f2bf(x); l[reg] = f2bf(x - bfhi(x));
            }
            uint2 hp, lp;
            hp.x = (unsigned)h[0] | ((unsigned)h[1] << 16);
            hp.y = (unsigned)h[2] | ((unsigned)h[3] << 16);
            lp.x = (unsigned)l[0] | ((unsigned)l[1] << 16);
            lp.y = (unsigned)l[2] | ((unsigned)l[3] << 16);
            *(uint2*)&dstH[n * 64 + m0] = hp;
            *(uint2*)&dstL[n * 64 + m0] = lp;
          }
        } else {  // H rows: [m][n]
#pragma unroll
          for (int nt = 0; nt < 4; ++nt) {
            const int n = 16 * nt + lm;
#pragma unroll
            for (int reg = 0; reg < 4; ++reg) {
              const int m = 16 * w + 4 * quad + reg;
              const float x = acc[nt][reg];
              dstH[m * 64 + n] = f2bf(x);
              dstL[m * 64 + n] = f2bf(x - bfhi(x));
            }
          }
        }
      }
    }
  } else {
    // B_bar chunk: dt * B_chunk @ Minv^T — all operands direct from global.
    const int d0 = (p - 128) * 64;
    const float dtv = expf(logdt[0]);
    const ushort_t* MvH = uspc(ws, WS_MV);
    const ushort_t* MvL = uspc(ws, WS_MV + 2048);
    f32x4v acc[4];
#pragma unroll
    for (int nt = 0; nt < 4; ++nt) { acc[nt][0] = acc[nt][1] = acc[nt][2] = acc[nt][3] = 0.f; }
#pragma unroll
    for (int c = 0; c < 2; ++c) {
      bf16x8 ahi, alo;
      ldsplit8(&Bg[(d0 + 16 * w + lm) * 64 + c * 32 + quad * 8], ahi, alo);
#pragma unroll
      for (int nt = 0; nt < 4; ++nt) {
        const int off = (16 * nt + lm) * 64 + c * 32 + quad * 8;
        const bf16x8 bh = *(const bf16x8*)&MvH[off];
        const bf16x8 bl = *(const bf16x8*)&MvL[off];
        acc[nt] = __builtin_amdgcn_mfma_f32_16x16x32_bf16(ahi, bh, acc[nt], 0, 0, 0);
        acc[nt] = __builtin_amdgcn_mfma_f32_16x16x32_bf16(ahi, bl, acc[nt], 0, 0, 0);
        acc[nt] = __builtin_amdgcn_mfma_f32_16x16x32_bf16(alo, bh, acc[nt], 0, 0, 0);
      }
    }
    float* od = ws + WS_BBAR + d0 * 64;
#pragma unroll
    for (int nt = 0; nt < 4; ++nt)
#pragma unroll
      for (int reg = 0; reg < 4; ++reg)
        od[(16 * w + 4 * quad + reg) * 64 + 16 * nt + lm] = dtv * acc[nt][reg];
  }
}

// ---------------------------------------------------------------------------
// K3: 512 blocks x 256, no LDS. Block = (chain, rr, dgrp); B-frags (Gt_rr or
// H_rr, pre-split) register-resident, reused over 4 d-chunks.
//  chain0: W[d][rr][j] = sum_n C[d,n] A^rr[n,j]
//  chain1: X[d][rr][j] = sum_k Bbar[d,k] H_rr[j,k]
// ---------------------------------------------------------------------------
__global__ __launch_bounds__(256) void k_expand(const float* __restrict__ Cg,
                                                float* __restrict__ ws) {
  const int p = blockIdx.x, tid = threadIdx.x;
  const int chain = p >> 8, rr = (p >> 2) & 63, dgrp = p & 3;
  const int w = tid >> 6, lane = tid & 63;
  const int lm = lane & 15, quad = lane >> 4;
  const int mb = (chain ? WS_H : WS_GT) + rr * 4096;
  const ushort_t* BtH = uspc(ws, mb);
  const ushort_t* BtL = uspc(ws, mb + 2048);

  bf16x8 bhi[2][4], blo[2][4];
#pragma unroll
  for (int c = 0; c < 2; ++c)
#pragma unroll
    for (int nt = 0; nt < 4; ++nt) {
      const int off = (16 * nt + lm) * 64 + c * 32 + quad * 8;
      bhi[c][nt] = *(const bf16x8*)&BtH[off];
      blo[c][nt] = *(const bf16x8*)&BtL[off];
    }

  for (int g = 0; g < 4; ++g) {
    const int d0 = (dgrp * 4 + g) * 64;
    const float* src = chain ? (ws + WS_BBAR + d0 * 64) : (Cg + d0 * 64);
    f32x4v acc[4];
#pragma unroll
    for (int nt = 0; nt < 4; ++nt) { acc[nt][0] = acc[nt][1] = acc[nt][2] = acc[nt][3] = 0.f; }
#pragma unroll
    for (int c = 0; c < 2; ++c) {
      bf16x8 ahi, alo;
      ldsplit8(&src[(16 * w + lm) * 64 + c * 32 + quad * 8], ahi, alo);
#pragma unroll
      for (int nt = 0; nt < 4; ++nt) {
        acc[nt] = __builtin_amdgcn_mfma_f32_16x16x32_bf16(ahi, bhi[c][nt], acc[nt], 0, 0, 0);
        acc[nt] = __builtin_amdgcn_mfma_f32_16x16x32_bf16(ahi, blo[c][nt], acc[nt], 0, 0, 0);
        acc[nt] = __builtin_amdgcn_mfma_f32_16x16x32_bf16(alo, bhi[c][nt], acc[nt], 0, 0, 0);
      }
    }
    float* dst = ws + (chain ? WS_X : WS_W) + d0 * 4096 + rr * 64;
#pragma unroll
    for (int nt = 0; nt < 4; ++nt)
#pragma unroll
      for (int reg = 0; reg < 4; ++reg)
        dst[(16 * w + 4 * quad + reg) * 4096 + 16 * nt + lm] = acc[nt][reg];
  }
}

// ---------------------------------------------------------------------------
// K4: 1024 blocks x 256, one block per d, no LDS, no barrier. Fragments
// loaded directly from global fp32 W/X, split in regs. + D[d] at l==0.
// ---------------------------------------------------------------------------
__global__ __launch_bounds__(256) void k_contract(const float* __restrict__ Dg,
                                                  const float* __restrict__ ws,
                                                  float* __restrict__ out) {
  const int d = blockIdx.x, tid = threadIdx.x;
  const int w = tid >> 6, lane = tid & 63;
  const int lm = lane & 15, quad = lane >> 4;
  const float* Xg = ws + WS_X + d * 4096;
  const float* Wg = ws + WS_W + d * 4096;

  f32x4v acc[4];
#pragma unroll
  for (int nt = 0; nt < 4; ++nt) { acc[nt][0] = acc[nt][1] = acc[nt][2] = acc[nt][3] = 0.f; }
#pragma unroll
  for (int c = 0; c < 2; ++c) {
    bf16x8 ahi, alo;
    ldsplit8(&Xg[(16 * w + lm) * 64 + c * 32 + quad * 8], ahi, alo);
#pragma unroll
    for (int nt = 0; nt < 4; ++nt) {
      bf16x8 bhi, blo;
      ldsplit8(&Wg[(16 * nt + lm) * 64 + c * 32 + quad * 8], bhi, blo);
      acc[nt] = __builtin_amdgcn_mfma_f32_16x16x32_bf16(ahi, bhi, acc[nt], 0, 0, 0);
      acc[nt] = __builtin_amdgcn_mfma_f32_16x16x32_bf16(ahi, blo, acc[nt], 0, 0, 0);
      acc[nt] = __builtin_amdgcn_mfma_f32_16x16x32_bf16(alo, bhi, acc[nt], 0, 0, 0);
    }
  }

  if (tid == 0) acc[0][0] += Dg[d];

  float* od = out + d * 4096;
#pragma unroll
  for (int nt = 0; nt < 4; ++nt) {
#pragma unroll
    for (int reg = 0; reg < 4; ++reg) {
      const int q = 16 * w + quad * 4 + reg;
      od[q * 64 + 16 * nt + lm] = acc[nt][reg];
    }
  }
}

extern "C" void kernel_launch(void* const* d_in, const int* in_sizes, int n_in,
                              void* d_out, int out_size, void* d_ws, size_t ws_size,
                              hipStream_t stream) {
  const float* A     = (const float*)d_in[0];  // A_ct 64x64
  const float* B     = (const float*)d_in[1];  // 1024x64
  const float* C     = (const float*)d_in[2];  // 1024x64
  const float* Dv    = (const float*)d_in[3];  // 1024
  const float* logdt = (const float*)d_in[4];  // scalar
  float* ws  = (float*)d_ws;
  float* out = (float*)d_out;                  // 1024*4096 fp32

  hipLaunchKernelGGL(k_setup,    dim3(1),    dim3(256), 0, stream, A, logdt, ws);
  hipLaunchKernelGGL(k_powers,   dim3(144),  dim3(256), 0, stream, B, logdt, ws);
  hipLaunchKernelGGL(k_expand,   dim3(512),  dim3(256), 0, stream, C, ws);
  hipLaunchKernelGGL(k_contract, dim3(1024), dim3(256), 0, stream, Dv, ws, out);
}

// Round 9
// 127.631 us; speedup vs baseline: 1.0613x; 1.0613x over previous
//
#include <hip/hip_runtime.h>
#include <math.h>

// HiPPO-LegS kernel: K[d, l] = C[d]^T A_bar^l B_bar[d], D=1024, N=64, L=4096.
// l = 64q + r decomposition; G_r = A_bar^r, H_q = (A_bar^64)^q via squarings
// S_j = A_bar^(2^j), j=0..11.  All products: mfma_f32_16x16x32_bf16 with
// split-bf16 hi/lo 3-term.
// Round 9: R7 structure restored (LDS-staged operands — R8's direct-global
// fragment loads regressed: more VMEM insts at ~200-900cyc latency vs staged
// ds_read at ~120). Only change vs R7: dstore_lds packs the Bt-half as
// ds_write_b64 (k_setup-local, 24 fewer LDS insts/thread/squaring).

#define BPAD 72  // bf16 LDS row stride in ushorts (144 B)
#define ARR (64 * BPAD)

// ws layout (float offsets).
#define WS_BBAR   16                      // 1024x64 fp32
#define WS_SPL    65552                   // 12 x 8192: [hi|lo|thi|tlo] x 2048 floats
#define WS_MV     (WS_SPL + 12*8192)      // MvHi 2048, MvLo 2048
#define WS_GT     (WS_MV + 4096)          // 64 x 4096 (hi 2048 | lo 2048)
#define WS_H      (WS_GT + 64*4096)       // 64 x 4096 (hi | lo)
#define WS_W      (WS_H + 64*4096)        // [d][r][n] fp32
#define WS_X      (WS_W + 1024*4096)      // [d][q][n] fp32

using bf16x8 = __attribute__((ext_vector_type(8))) short;
using f32x4v = __attribute__((ext_vector_type(4))) float;
typedef unsigned short ushort_t;

__device__ __forceinline__ ushort_t f2bf(float x) {
  unsigned u = __builtin_bit_cast(unsigned, x);
  return (ushort_t)((u + 0x7FFFu + ((u >> 16) & 1u)) >> 16);
}
__device__ __forceinline__ float bfhi(float x) {
  unsigned u = __builtin_bit_cast(unsigned, x);
  unsigned r = (u + 0x7FFFu + ((u >> 16) & 1u)) & 0xFFFF0000u;
  return __builtin_bit_cast(float, r);
}
__device__ __forceinline__ ushort_t* usp(float* ws, int foff) {
  return (ushort_t*)(ws + foff);
}
__device__ __forceinline__ const ushort_t* uspc(const float* ws, int foff) {
  return (const ushort_t*)(ws + foff);
}

// ---- MFMA 64x64x64: D[m][n] = sum_k A[m][k]*Bt[n][k], split-bf16 3-term ----
// A-layout LDS [m][k] (BPAD), Bt-layout LDS [n][k]. Wave w owns m in [16w,16w+16).
__device__ __forceinline__ void mm_frag(const ushort_t* __restrict__ Ah,
                                        const ushort_t* __restrict__ Al,
                                        const ushort_t* __restrict__ Bh,
                                        const ushort_t* __restrict__ Bl,
                                        int w, int lane, f32x4v acc[4]) {
  const int lm = lane & 15, quad = lane >> 4;
  const int ar = (16 * w + lm) * BPAD, ko = quad * 8;
#pragma unroll
  for (int nt = 0; nt < 4; ++nt) { acc[nt][0] = acc[nt][1] = acc[nt][2] = acc[nt][3] = 0.f; }
#pragma unroll
  for (int kc = 0; kc < 64; kc += 32) {
    const bf16x8 ahi = *(const bf16x8*)&Ah[ar + kc + ko];
    const bf16x8 alo = *(const bf16x8*)&Al[ar + kc + ko];
#pragma unroll
    for (int nt = 0; nt < 4; ++nt) {
      const int br = (16 * nt + lm) * BPAD + kc + ko;
      const bf16x8 bhi = *(const bf16x8*)&Bh[br];
      const bf16x8 blo = *(const bf16x8*)&Bl[br];
      acc[nt] = __builtin_amdgcn_mfma_f32_16x16x32_bf16(ahi, bhi, acc[nt], 0, 0, 0);
      acc[nt] = __builtin_amdgcn_mfma_f32_16x16x32_bf16(ahi, blo, acc[nt], 0, 0, 0);
      acc[nt] = __builtin_amdgcn_mfma_f32_16x16x32_bf16(alo, bhi, acc[nt], 0, 0, 0);
    }
  }
}

// D regs -> split bf16 LDS in BOTH layouts. A-layout scalar (transposed
// scatter), Bt-layout b64-packed over reg (contiguous m0..m0+3).
__device__ __forceinline__ void dstore_lds(const f32x4v acc[4],
                                           ushort_t* __restrict__ Ah, ushort_t* __restrict__ Al,
                                           ushort_t* __restrict__ Bth, ushort_t* __restrict__ Btl,
                                           int w, int lane) {
  const int lm = lane & 15, quad = lane >> 4;
  const int m0 = 16 * w + 4 * quad;
#pragma unroll
  for (int nt = 0; nt < 4; ++nt) {
    const int n = 16 * nt + lm;
    ushort_t h[4], l[4];
#pragma unroll
    for (int reg = 0; reg < 4; ++reg) {
      const float x = acc[nt][reg];
      h[reg] = f2bf(x); l[reg] = f2bf(x - bfhi(x));
      Ah[(m0 + reg) * BPAD + n] = h[reg];
      Al[(m0 + reg) * BPAD + n] = l[reg];
    }
    uint2 hp, lp;
    hp.x = (unsigned)h[0] | ((unsigned)h[1] << 16);
    hp.y = (unsigned)h[2] | ((unsigned)h[3] << 16);
    lp.x = (unsigned)l[0] | ((unsigned)l[1] << 16);
    lp.y = (unsigned)l[2] | ((unsigned)l[3] << 16);
    *(uint2*)&Bth[n * BPAD + m0] = hp;
    *(uint2*)&Btl[n * BPAD + m0] = lp;
  }
}

// packed 64x64 ushort ws region <-> padded LDS (BPAD), 256 threads
__device__ __forceinline__ void cp_l2w(const ushort_t* __restrict__ l,
                                       ushort_t* __restrict__ g, int tid) {
  for (int e = tid; e < 512; e += 256) {
    const int row = e >> 3, c8 = (e & 7) * 8;
    *(uint4*)&g[row * 64 + c8] = *(const uint4*)&l[row * BPAD + c8];
  }
}
__device__ __forceinline__ void cp_w2l(const ushort_t* __restrict__ g,
                                       ushort_t* __restrict__ l, int tid) {
  for (int e = tid; e < 512; e += 256) {
    const int row = e >> 3, c8 = (e & 7) * 8;
    *(uint4*)&l[row * BPAD + c8] = *(const uint4*)&g[row * 64 + c8];
  }
}

// fp32 global 64x64 -> split bf16 A-layout LDS, 256 threads
__device__ __forceinline__ void split_stage(const float* __restrict__ g,
                                            ushort_t* __restrict__ Ah,
                                            ushort_t* __restrict__ Al, int tid) {
#pragma unroll
  for (int j = 0; j < 4; ++j) {
    const int flat = j * 1024 + tid * 4;
    const int row = flat >> 6, col = flat & 63;
    const float4 v = *(const float4*)&g[flat];
    ushort_t h0 = f2bf(v.x), h1 = f2bf(v.y), h2 = f2bf(v.z), h3 = f2bf(v.w);
    ushort_t l0 = f2bf(v.x - bfhi(v.x)), l1 = f2bf(v.y - bfhi(v.y));
    ushort_t l2 = f2bf(v.z - bfhi(v.z)), l3 = f2bf(v.w - bfhi(v.w));
    uint2 hp, lp;
    hp.x = (unsigned)h0 | ((unsigned)h1 << 16); hp.y = (unsigned)h2 | ((unsigned)h3 << 16);
    lp.x = (unsigned)l0 | ((unsigned)l1 << 16); lp.y = (unsigned)l2 | ((unsigned)l3 << 16);
    *(uint2*)&Ah[row * BPAD + col] = hp;
    *(uint2*)&Al[row * BPAD + col] = lp;
  }
}

// ---------------------------------------------------------------------------
// K1: one block, 256 threads. fp32 recursive-doubling inverse of lower-tri M
// (diag >= 1.05); A_bar = 2*Minv - I; 11 MFMA split-bf16 squarings, state as
// hi/lo bf16 in A + Bt LDS layouts. Exports S_j / S_j^T / Minv (split).
// ---------------------------------------------------------------------------
__global__ __launch_bounds__(256) void k_setup(const float* __restrict__ A,
                                               const float* __restrict__ logdt,
                                               float* __restrict__ ws) {
  __shared__ __align__(16) char SM[74240];
  float* Msh = (float*)SM;                    // 64*65 fp32, dead after phase 2
  float* Tm  = (float*)(SM + 16640);          // 64*65 fp32 (becomes Minv)
  float* tmpb = (float*)(SM + 33280);         // 1024 fp32
  ushort_t* ping = (ushort_t*)(SM + 37376);   // 4 arrays of ARR
  ushort_t* pong = (ushort_t*)SM;             // overlays Msh/Tm/tmpb (dead then)
  const int tid = threadIdx.x;
  const int w = tid >> 6, lane = tid & 63;

  const float hdt = 0.5f * expf(logdt[0]);
  for (int idx = tid; idx < 4096; idx += 256) {
    const int i = idx >> 6, j = idx & 63;
    Msh[i * 65 + j] = ((i == j) ? 1.f : 0.f) - hdt * A[idx];
    Tm[i * 65 + j] = 0.f;
  }
  __syncthreads();
  if (tid < 64) Tm[tid * 65 + tid] = 1.0f / Msh[tid * 65 + tid];
  __syncthreads();
  for (int lb = 0; lb < 6; ++lb) {
    const int b = 1 << lb;
    const int E = 32 * b;
    for (int e = tid; e < E; e += 256) {
      const int rem = e & (b * b - 1);
      const int p = e >> (2 * lb);
      const int i = rem >> lb, j = rem & (b - 1);
      const int c0 = p << (lb + 1), r0 = c0 + b;
      float s = 0.f;
      for (int k = 0; k < b; ++k)
        s += Msh[(r0 + i) * 65 + c0 + k] * Tm[(c0 + k) * 65 + c0 + j];
      tmpb[e] = s;
    }
    __syncthreads();
    for (int e = tid; e < E; e += 256) {
      const int rem = e & (b * b - 1);
      const int p = e >> (2 * lb);
      const int i = rem >> lb, j = rem & (b - 1);
      const int c0 = p << (lb + 1), r0 = c0 + b;
      float s = 0.f;
      const float* tp = &tmpb[e - rem];
      for (int k = 0; k < b; ++k)
        s += Tm[(r0 + i) * 65 + r0 + k] * tp[k * b + j];
      Tm[(r0 + i) * 65 + c0 + j] = -s;
    }
    __syncthreads();
  }

  {
    ushort_t* MvH = usp(ws, WS_MV);
    ushort_t* MvL = usp(ws, WS_MV + 2048);
    for (int idx = tid; idx < 4096; idx += 256) {
      const int i = idx >> 6, j = idx & 63;
      const float mv = Tm[i * 65 + j];
      MvH[idx] = f2bf(mv); MvL[idx] = f2bf(mv - bfhi(mv));
      const float v = 2.f * mv - ((i == j) ? 1.f : 0.f);
      const ushort_t h = f2bf(v), l = f2bf(v - bfhi(v));
      ping[0 * ARR + i * BPAD + j] = h; ping[1 * ARR + i * BPAD + j] = l;
      ping[2 * ARR + j * BPAD + i] = h; ping[3 * ARR + j * BPAD + i] = l;
    }
  }
  __syncthreads();
  cp_l2w(ping + 0 * ARR, usp(ws, WS_SPL + 0), tid);
  cp_l2w(ping + 1 * ARR, usp(ws, WS_SPL + 2048), tid);
  cp_l2w(ping + 2 * ARR, usp(ws, WS_SPL + 4096), tid);
  cp_l2w(ping + 3 * ARR, usp(ws, WS_SPL + 6144), tid);

  ushort_t* cur = ping;
  ushort_t* nxt = pong;
  for (int sj = 1; sj < 12; ++sj) {
    f32x4v acc[4];
    mm_frag(cur, cur + ARR, cur + 2 * ARR, cur + 3 * ARR, w, lane, acc);
    dstore_lds(acc, nxt, nxt + ARR, nxt + 2 * ARR, nxt + 3 * ARR, w, lane);
    __syncthreads();
    const int base = WS_SPL + sj * 8192;
    cp_l2w(nxt + 0 * ARR, usp(ws, base + 0), tid);
    cp_l2w(nxt + 1 * ARR, usp(ws, base + 2048), tid);
    cp_l2w(nxt + 2 * ARR, usp(ws, base + 4096), tid);
    cp_l2w(nxt + 3 * ARR, usp(ws, base + 6144), tid);
    ushort_t* t = cur; cur = nxt; nxt = t;
  }
}

// ---------------------------------------------------------------------------
// K2: 144 blocks x 256. (R7 version — LDS-staged operands)
//  p in [0,64):   Gt_r = (A^r)^T split  (product over set bits, MFMA)
//  p in [64,128): H_q  = A^(64q) split  (row-major)
//  p in [128,144): B_bar chunk = dt * B @ Minv^T (MFMA, fp32 out)
// ---------------------------------------------------------------------------
__global__ __launch_bounds__(256) void k_powers(const float* __restrict__ Bg,
                                                const float* __restrict__ logdt,
                                                float* __restrict__ ws) {
  __shared__ __align__(16) ushort_t SMp[8 * ARR];  // 73.7 KB
  ushort_t* curA = SMp;                 // 2 arrays (hi,lo)
  ushort_t* ponA = SMp + 2 * ARR;       // 2 arrays
  ushort_t* Bst  = SMp + 4 * ARR;       // 2 arrays (staged Bt operand)
  ushort_t* BtO  = SMp + 6 * ARR;       // 2 arrays (transposed result)
  const int p = blockIdx.x, tid = threadIdx.x;
  const int w = tid >> 6, lane = tid & 63;

  if (p < 128) {
    const int chain = p >> 6, r = p & 63;
    ushort_t* dstH = usp(ws, (chain ? WS_H : WS_GT) + r * 4096);
    ushort_t* dstL = usp(ws, (chain ? WS_H : WS_GT) + r * 4096 + 2048);
    if (r == 0) {  // identity
      for (int idx = tid; idx < 4096; idx += 256) {
        const int i = idx >> 6, j = idx & 63;
        dstH[idx] = (i == j) ? (ushort_t)0x3F80 : (ushort_t)0;
        dstL[idx] = 0;
      }
      return;
    }
    const int j0 = __ffs(r) - 1;
    if (r == (1 << j0)) {  // single bit: straight ws->ws copy
      const int sb = WS_SPL + (chain * 6 + j0) * 8192;
      const int src = chain ? sb : (sb + 4096);  // chain0: St, chain1: S
      const uint4* sh = (const uint4*)uspc(ws, src);
      const uint4* sl = (const uint4*)uspc(ws, src + 2048);
      uint4* dh = (uint4*)dstH;
      uint4* dl = (uint4*)dstL;
      for (int e = tid; e < 512; e += 256) { dh[e] = sh[e]; dl[e] = sl[e]; }
      return;
    }
    // multi-bit chain
    {
      const int sb = WS_SPL + (chain * 6 + j0) * 8192;  // S_{j0} row-major split
      cp_w2l(uspc(ws, sb + 0), curA, tid);
      cp_w2l(uspc(ws, sb + 2048), curA + ARR, tid);
    }
    ushort_t* ca = curA;
    ushort_t* na = ponA;
    for (int j = j0 + 1; j < 6; ++j) {
      if ((r >> j) & 1) {  // block-uniform
        __syncthreads();
        const int sb = WS_SPL + (chain * 6 + j) * 8192;
        cp_w2l(uspc(ws, sb + 4096), Bst, tid);        // St_j hi
        cp_w2l(uspc(ws, sb + 6144), Bst + ARR, tid);  // St_j lo
        __syncthreads();
        f32x4v acc[4];
        mm_frag(ca, ca + ARR, Bst, Bst + ARR, w, lane, acc);
        dstore_lds(acc, na, na + ARR, BtO, BtO + ARR, w, lane);
        ushort_t* t = ca; ca = na; na = t;
      }
    }
    __syncthreads();
    if (chain == 0) {  // Gt = (result)^T
      cp_l2w(BtO, dstH, tid);
      cp_l2w(BtO + ARR, dstL, tid);
    } else {           // H = result row-major
      cp_l2w(ca, dstH, tid);
      cp_l2w(ca + ARR, dstL, tid);
    }
  } else {
    // B_bar chunk: dt * B_chunk @ Minv^T. Bt-frag rows = Minv rows.
    const int d0 = (p - 128) * 64;
    const float dtv = expf(logdt[0]);
    split_stage(Bg + d0 * 64, curA, curA + ARR, tid);
    cp_w2l(uspc(ws, WS_MV), Bst, tid);
    cp_w2l(uspc(ws, WS_MV + 2048), Bst + ARR, tid);
    __syncthreads();
    f32x4v acc[4];
    mm_frag(curA, curA + ARR, Bst, Bst + ARR, w, lane, acc);
    const int lm = lane & 15, quad = lane >> 4;
    float* od = ws + WS_BBAR + d0 * 64;
#pragma unroll
    for (int nt = 0; nt < 4; ++nt)
#pragma unroll
      for (int reg = 0; reg < 4; ++reg)
        od[(16 * w + 4 * quad + reg) * 64 + 16 * nt + lm] = dtv * acc[nt][reg];
  }
}

// ---------------------------------------------------------------------------
// K3: 2048 blocks x 256. (R7 version) Block = (chain, rr, dch).
//  chain0: W[d0..][rr][j] = sum_n C[d,n] A^rr[n,j]   (Bt = Gt_rr, pre-split)
//  chain1: X[d0..][rr][j] = sum_k Bbar[d,k] H_rr[j,k] (Bt = H_rr, pre-split)
// LDS 36.9 KB -> 4 blocks/CU.
// ---------------------------------------------------------------------------
__global__ __launch_bounds__(256) void k_expand(const float* __restrict__ Cg,
                                                float* __restrict__ ws) {
  __shared__ __align__(16) ushort_t SMe[4 * ARR];
  ushort_t* Asp = SMe;            // hi, lo
  ushort_t* Bsp = SMe + 2 * ARR;  // hi, lo
  const int p = blockIdx.x, tid = threadIdx.x;
  const int chain = p >> 10, rr = (p >> 4) & 63, dch = p & 15;
  const int w = tid >> 6, lane = tid & 63;
  const int d0 = dch * 64;

  split_stage(chain ? (ws + WS_BBAR + d0 * 64) : (Cg + d0 * 64), Asp, Asp + ARR, tid);
  const int mb = (chain ? WS_H : WS_GT) + rr * 4096;
  cp_w2l(uspc(ws, mb + 0), Bsp, tid);
  cp_w2l(uspc(ws, mb + 2048), Bsp + ARR, tid);
  __syncthreads();

  f32x4v acc[4];
  mm_frag(Asp, Asp + ARR, Bsp, Bsp + ARR, w, lane, acc);

  const int lm = lane & 15, quad = lane >> 4;
  float* dst = ws + (chain ? WS_X : WS_W) + d0 * 4096 + rr * 64;
#pragma unroll
  for (int nt = 0; nt < 4; ++nt)
#pragma unroll
    for (int reg = 0; reg < 4; ++reg)
      dst[(16 * w + 4 * quad + reg) * 4096 + 16 * nt + lm] = acc[nt][reg];
}

// ---------------------------------------------------------------------------
// K4: 1024 blocks x 256, one block per d — MFMA split-bf16, LDS-staged (R7).
// ---------------------------------------------------------------------------
__global__ __launch_bounds__(256) void k_contract(const float* __restrict__ Dg,
                                                  const float* __restrict__ ws,
                                                  float* __restrict__ out) {
  __shared__ __align__(16) ushort_t XhiL[64 * BPAD];
  __shared__ __align__(16) ushort_t XloL[64 * BPAD];
  __shared__ __align__(16) ushort_t WhiL[64 * BPAD];
  __shared__ __align__(16) ushort_t WloL[64 * BPAD];
  const int d = blockIdx.x, tid = threadIdx.x;
  const float* Wg = ws + WS_W + d * 4096;
  const float* Xg = ws + WS_X + d * 4096;

#pragma unroll
  for (int j = 0; j < 4; ++j) {
    const int flat = j * 1024 + tid * 4;
    const int row = flat >> 6, col = flat & 63;
    const float4 wv = *(const float4*)&Wg[flat];
    const float4 xv = *(const float4*)&Xg[flat];
    const int o = row * BPAD + col;
#pragma unroll
    for (int s = 0; s < 2; ++s) {
      const float4 v = s ? xv : wv;
      ushort_t h0 = f2bf(v.x), h1 = f2bf(v.y), h2 = f2bf(v.z), h3 = f2bf(v.w);
      ushort_t l0 = f2bf(v.x - bfhi(v.x)), l1 = f2bf(v.y - bfhi(v.y));
      ushort_t l2 = f2bf(v.z - bfhi(v.z)), l3 = f2bf(v.w - bfhi(v.w));
      uint2 hp, lp;
      hp.x = (unsigned)h0 | ((unsigned)h1 << 16); hp.y = (unsigned)h2 | ((unsigned)h3 << 16);
      lp.x = (unsigned)l0 | ((unsigned)l1 << 16); lp.y = (unsigned)l2 | ((unsigned)l3 << 16);
      *(uint2*)&(s ? XhiL : WhiL)[o] = hp;
      *(uint2*)&(s ? XloL : WloL)[o] = lp;
    }
  }
  __syncthreads();

  const int w = tid >> 6, lane = tid & 63;
  const int lm = lane & 15, quad = lane >> 4;
  const int qrow = 16 * w + lm;
  const int koff = quad * 8;

  f32x4v acc[4];
#pragma unroll
  for (int nt = 0; nt < 4; ++nt) { acc[nt][0] = 0.f; acc[nt][1] = 0.f; acc[nt][2] = 0.f; acc[nt][3] = 0.f; }

#pragma unroll
  for (int kc = 0; kc < 64; kc += 32) {
    const bf16x8 ahi = *(const bf16x8*)&XhiL[qrow * BPAD + kc + koff];
    const bf16x8 alo = *(const bf16x8*)&XloL[qrow * BPAD + kc + koff];
#pragma unroll
    for (int nt = 0; nt < 4; ++nt) {
      const int rrow = 16 * nt + lm;
      const bf16x8 bhi = *(const bf16x8*)&WhiL[rrow * BPAD + kc + koff];
      const bf16x8 blo = *(const bf16x8*)&WloL[rrow * BPAD + kc + koff];
      acc[nt] = __builtin_amdgcn_mfma_f32_16x16x32_bf16(ahi, bhi, acc[nt], 0, 0, 0);
      acc[nt] = __builtin_amdgcn_mfma_f32_16x16x32_bf16(ahi, blo, acc[nt], 0, 0, 0);
      acc[nt] = __builtin_amdgcn_mfma_f32_16x16x32_bf16(alo, bhi, acc[nt], 0, 0, 0);
    }
  }

  if (tid == 0) acc[0][0] += Dg[d];

  float* od = out + d * 4096;
#pragma unroll
  for (int nt = 0; nt < 4; ++nt) {
#pragma unroll
    for (int reg = 0; reg < 4; ++reg) {
      const int q = 16 * w + quad * 4 + reg;
      od[q * 64 + 16 * nt + lm] = acc[nt][reg];
    }
  }
}

extern "C" void kernel_launch(void* const* d_in, const int* in_sizes, int n_in,
                              void* d_out, int out_size, void* d_ws, size_t ws_size,
                              hipStream_t stream) {
  const float* A     = (const float*)d_in[0];  // A_ct 64x64
  const float* B     = (const float*)d_in[1];  // 1024x64
  const float* C     = (const float*)d_in[2];  // 1024x64
  const float* Dv    = (const float*)d_in[3];  // 1024
  const float* logdt = (const float*)d_in[4];  // scalar
  float* ws  = (float*)d_ws;
  float* out = (float*)d_out;                  // 1024*4096 fp32

  hipLaunchKernelGGL(k_setup,    dim3(1),    dim3(256), 0, stream, A, logdt, ws);
  hipLaunchKernelGGL(k_powers,   dim3(144),  dim3(256), 0, stream, B, logdt, ws);
  hipLaunchKernelGGL(k_expand,   dim3(2048), dim3(256), 0, stream, C, ws);
  hipLaunchKernelGGL(k_contract, dim3(1024), dim3(256), 0, stream, Dv, ws, out);
}